// Round 14
// baseline (509.007 us; speedup 1.0000x reference)
//
#include <hip/hip_runtime.h>
#include <cstdint>
#include <cstddef>

// Problem constants
#define B_ 8
#define S_ 4096
#define H_ 1024
#define NH_ 16
#define DH_ 64
#define MTOK 32768  // B_*S_

typedef unsigned short u16;
typedef __bf16 bf16x8 __attribute__((ext_vector_type(8)));
typedef u16 u16x8 __attribute__((ext_vector_type(8)));
typedef u16 u16x4 __attribute__((ext_vector_type(4)));
typedef float f32x4 __attribute__((ext_vector_type(4)));

#define DEVFN static __device__ __forceinline__

DEVFN float bf2f(u16 u) {
  union { uint32_t u; float f; } c; c.u = ((uint32_t)u) << 16; return c.f;
}
DEVFN u16 f2bf(float f) {
  union { float f; uint32_t u; } c; c.f = f;
  uint32_t r = c.u + 0x7fffu + ((c.u >> 16) & 1u);  // RNE
  return (u16)(r >> 16);
}
DEVFN void gload16(const void* g, void* lds_p) {
  __builtin_amdgcn_global_load_lds(
      (const __attribute__((address_space(1))) void*)g,
      (__attribute__((address_space(3))) void*)lds_p, 16, 0, 0);
}

// Fragment-linear B layout ("Bp"): for chunk (n16, ks) the 1KB block holds,
// at lane-slot lf = 0..63, the 8 bf16 B^T[n16*16 + (lf&15)][ks*32 + (lf>>4)*8
// .. +7]. A wave's MFMA B-operand load is then ONE coalesced 1KB dwordx4.

// ---------------------------------------------------------------------------
// Convert fp32 X -> bf16 Xb
__global__ __launch_bounds__(256) void k_cvt_x(const float* __restrict__ x,
                                               u16* __restrict__ xb) {
  const size_t i = ((size_t)blockIdx.x * 256 + threadIdx.x) * 8;
  f32x4 a = *(const f32x4*)(x + i);
  f32x4 b = *(const f32x4*)(x + i + 4);
  u16x8 o;
#pragma unroll
  for (int j = 0; j < 4; ++j) { o[j] = f2bf(a[j]); o[4 + j] = f2bf(b[j]); }
  *(u16x8*)(xb + i) = o;
}

// ---------------------------------------------------------------------------
// Weight prep:
// g<3:  Bp fragment-packed QKV weights (n16 spans g*64..), 6MB total.
// g==3: Wdt[n][e] = Wd[e][n]  (plain B^T for k_m2's LDS path)
__global__ __launch_bounds__(256) void k_wt(const float* __restrict__ Wq,
                                            const float* __restrict__ Wk,
                                            const float* __restrict__ Wv,
                                            const float* __restrict__ Wd,
                                            u16* __restrict__ Bp,
                                            u16* __restrict__ Wdt) {
  const int n = blockIdx.x * 256 + threadIdx.x;  // 0..1023
  const int kc = blockIdx.y;                     // k-octet 0..127
  const int g = blockIdx.z;                      // 0..3
  const float* W = (g == 0) ? Wq : (g == 1) ? Wk : (g == 2) ? Wv : Wd;
  u16x8 o;
#pragma unroll
  for (int j = 0; j < 8; ++j) o[j] = f2bf(W[(size_t)(kc * 8 + j) * 1024 + n]);
  if (g < 3) {
    const int gn = g * 1024 + n;
    const int n16 = gn >> 4, ks = kc >> 2;
    const int lf = (gn & 15) | ((kc & 3) << 4);
    *(u16x8*)(Bp + ((size_t)(n16 * 32 + ks)) * 512 + lf * 8) = o;
  } else {
    *(u16x8*)(Wdt + (size_t)n * 1024 + kc * 8) = o;
  }
}

// ---------------------------------------------------------------------------
// GEMM: 128x256 tile, BK=64, 512 threads = 8 waves (2Mx4N).
// A: LDS-staged (16KB, gload_lds, XOR slot swizzle -> 2-way banks = free),
// B: DIRECT global->VGPR from fragment-packed Bp (coalesced 1KB loads,
//    L2/L3-resident weights) -- no B in LDS, drain shrinks to A-only.
// Plain __syncthreads per K-tile; direct scalar stores (R1 epilogue).
// XCD-chunked grid: xcd=bid&7 owns 32 consecutive bx; by cycles fastest.
// EPI=0: QKV (bias + elu for Q,K), grid 3072 = 8 x (12 by x 32 bx).
// EPI=1: ctx (plain store, Bp per-batch +b<<20), grid 1024 = 8 x (4 by x 32).
template <int EPI>
__global__ __launch_bounds__(512, 2) void k_g(
    const u16* __restrict__ A, const u16* __restrict__ Bp,
    u16* __restrict__ o0, u16* __restrict__ o1, u16* __restrict__ o2,
    const float* __restrict__ b0, const float* __restrict__ b1,
    const float* __restrict__ b2) {
  __shared__ u16 As[2 * 128 * 32];  // 16KB [kh][128 rows][32 u16]
  const int tid = threadIdx.x;
  const int w = tid >> 6, l = tid & 63;
  const int wm = w >> 2, wn = w & 3;  // 2M x 4N waves

  const int bid = (int)blockIdx.x;
  const int xcd = bid & 7, c = bid >> 3;
  int bx, by;
  if (EPI == 0) { by = c % 12; bx = xcd * 32 + c / 12; }
  else          { by = c & 3;  bx = xcd * 32 + (c >> 2); }

  const long row0 = (long)bx * 128;
  const long col0 = (long)by * 256;
  const u16* Bq = Bp + (EPI == 1 ? ((size_t)(row0 >> 12) << 20) : (size_t)0);

  f32x4 acc[4][4];
#pragma unroll
  for (int i = 0; i < 4; ++i)
#pragma unroll
    for (int j = 0; j < 4; ++j) acc[i][j] = (f32x4){0.f, 0.f, 0.f, 0.f};

  // A staging: row tid>>2, 16B slot (tid&3) pre-swizzled by ((row>>1)&3);
  // linear LDS dest (chunk tid per kh half).
  const int asl = ((tid & 3) ^ ((tid >> 3) & 3)) * 8;  // u16 offset
  const u16* gA = A + (row0 + (tid >> 2)) * 1024 + asl;
  u16* lA = As + w * 512;  // wave-uniform; +4096 u16 for kh=1

  // A read base: row*32 + swizzled slot (u16); + mi*512 + kh*4096
  const int aoff = (wm * 64 + (l & 15)) * 32 + (((l >> 4) ^ ((l >> 1) & 3)) << 3);

  // B chunk row base: n16 = col0/16 + wn*4 + nf
  const int n16b = (int)(col0 >> 4) + wn * 4;
  const size_t loff = (size_t)l * 8;

  for (int kt = 0; kt < 1024; kt += 64) {
    // stage A (2 chunks: kh0, kh1)
    gload16(gA + kt, lA);
    gload16(gA + kt + 32, lA + 4096);
    // B fragment loads for both kh (latency hides under the A drain)
    const int ks0 = kt >> 5;
    bf16x8 bq0[4], bq1[4];
#pragma unroll
    for (int nf = 0; nf < 4; ++nf) {
      const size_t ch = (size_t)((n16b + nf) * 32 + ks0) * 512;
      bq0[nf] = *(const bf16x8*)(Bq + ch + loff);
      bq1[nf] = *(const bf16x8*)(Bq + ch + 512 + loff);
    }
    __syncthreads();  // drains vmcnt -> A tile visible
#pragma unroll
    for (int kh = 0; kh < 2; ++kh) {
      bf16x8 af[4];
#pragma unroll
      for (int mi = 0; mi < 4; ++mi)
        af[mi] = *(const bf16x8*)(As + kh * 4096 + aoff + mi * 512);
#pragma unroll
      for (int mi = 0; mi < 4; ++mi)
#pragma unroll
        for (int nf = 0; nf < 4; ++nf)
          acc[mi][nf] = __builtin_amdgcn_mfma_f32_16x16x32_bf16(
              af[mi], kh ? bq1[nf] : bq0[nf], acc[mi][nf], 0, 0, 0);
    }
    __syncthreads();  // all A reads done before next stage overwrites
  }

  // Epilogue: D row = (l>>4)*4+reg, col = l&15 within each 16x16 frag
  const int rb = (int)row0 + wm * 64 + ((l >> 4) << 2);
  const int cb = (int)col0 + wn * 64 + (l & 15);
  if (EPI == 0) {
    const int seg = (int)(col0 >> 10);  // 0:Q 1:K 2:V (uniform per block)
    const int cl = cb & 1023;
    u16* outp = (seg == 0) ? o0 : (seg == 1) ? o1 : o2;
    const float* bias = (seg == 0) ? b0 : (seg == 1) ? b1 : b2;
#pragma unroll
    for (int mi = 0; mi < 4; ++mi)
#pragma unroll
      for (int ni = 0; ni < 4; ++ni) {
        const float bv_ = bias[cl + ni * 16];
#pragma unroll
        for (int r = 0; r < 4; ++r) {
          float v = acc[mi][ni][r] + bv_;
          if (seg < 2) v = v > 0.f ? v : expm1f(v);  // elu
          outp[(size_t)(rb + mi * 16 + r) * 1024 + cl + ni * 16] = f2bf(v);
        }
      }
  } else {
#pragma unroll
    for (int mi = 0; mi < 4; ++mi)
#pragma unroll
      for (int ni = 0; ni < 4; ++ni)
#pragma unroll
        for (int r = 0; r < 4; ++r)
          o0[(size_t)(rb + mi * 16 + r) * 1024 + cb + ni * 16] =
              f2bf(acc[mi][ni][r]);
  }
}

// ---------------------------------------------------------------------------
// Per-(token,head) L2 norm for Q only, in place (K norm fused into k_kv).
__global__ __launch_bounds__(256) void k_qn(u16* __restrict__ eq) {
  const int tid = threadIdx.x, w = tid >> 6, l = tid & 63;
  const long t = (long)blockIdx.x * 4 + w;
  const size_t base = (size_t)t * 1024 + (l >> 2) * 64 + (l & 3) * 16;
  u16x8 a = *(const u16x8*)(eq + base);
  u16x8 b = *(const u16x8*)(eq + base + 8);
  float f[16];
#pragma unroll
  for (int j = 0; j < 8; ++j) { f[j] = bf2f(a[j]); f[8 + j] = bf2f(b[j]); }
  float ss = 0.f;
#pragma unroll
  for (int j = 0; j < 16; ++j) ss += f[j] * f[j];
  ss += __shfl_xor(ss, 1);
  ss += __shfl_xor(ss, 2);
  const float rq = rsqrtf(ss);
  u16x8 oa, ob;
#pragma unroll
  for (int j = 0; j < 8; ++j) { oa[j] = f2bf(f[j] * rq); ob[j] = f2bf(f[8 + j] * rq); }
  *(u16x8*)(eq + base) = oa;
  *(u16x8*)(eq + base + 8) = ob;
}

// ---------------------------------------------------------------------------
// kv partials via MFMA with FUSED K-normalization:
// kvp[sc][b][h][d][e] = sum_{s in quarter} (ek[s,d]/||ek[s,:]||) * v[s,e]
__global__ __launch_bounds__(256) void k_kv(const u16* __restrict__ ek,
                                            const u16* __restrict__ vv,
                                            float* __restrict__ kvp) {
  __shared__ __align__(16) char lds[69632];  // 4 regions x 17408 B
  const int tid = threadIdx.x, w = tid >> 6, l = tid & 63;
  const int bid = blockIdx.x;  // sc + 4*(h + 16*b)
  const int sc = bid & 3, h = (bid >> 2) & 15, b = bid >> 6;
  const int tp = l >> 3, dgrp = l & 7;
  char* myk = lds + w * 17408;       // knT tile [64 d][64 s] u16 (128B rows)
  char* myv = myk + 8192;            // vT tile
  const long Tw = (long)b * 4096 + sc * 1024 + w * 256;
  const int d0 = dgrp * 8;

  f32x4 acc[4][4];
#pragma unroll
  for (int i = 0; i < 4; ++i)
#pragma unroll
    for (int j = 0; j < 4; ++j) acc[i][j] = (f32x4){0.f, 0.f, 0.f, 0.f};

  for (int st = 0; st < 4; ++st) {
    // ---- transpose-stage 64 tokens x 64 d for kn (normalized) and v
#pragma unroll
    for (int ro = 0; ro < 4; ++ro) {
      const int tl = ro * 16 + tp * 2;  // even local token
      const long T = Tw + st * 64 + tl;
      const u16* kp = ek + (size_t)T * 1024 + h * 64 + d0;
      const u16* vp = vv + (size_t)T * 1024 + h * 64 + d0;
      u16x8 k0 = *(const u16x8*)kp, k1 = *(const u16x8*)(kp + 1024);
      u16x8 v0 = *(const u16x8*)vp, v1 = *(const u16x8*)(vp + 1024);
      float f0[8], f1[8], s0 = 0.f, s1 = 0.f;
#pragma unroll
      for (int j = 0; j < 8; ++j) {
        f0[j] = bf2f(k0[j]); s0 += f0[j] * f0[j];
        f1[j] = bf2f(k1[j]); s1 += f1[j] * f1[j];
      }
      s0 += __shfl_xor(s0, 1); s0 += __shfl_xor(s0, 2); s0 += __shfl_xor(s0, 4);
      s1 += __shfl_xor(s1, 1); s1 += __shfl_xor(s1, 2); s1 += __shfl_xor(s1, 4);
      const float r0 = rsqrtf(s0), r1 = rsqrtf(s1);
#pragma unroll
      for (int j = 0; j < 8; ++j) {
        const int d = d0 + j;
        const int sw = (d & 8) ? 32 : 0;
        *(uint32_t*)(myk + d * 128 + ((tl * 2) ^ sw)) =
            (uint32_t)f2bf(f0[j] * r0) | ((uint32_t)f2bf(f1[j] * r1) << 16);
        *(uint32_t*)(myv + d * 128 + ((tl * 2) ^ sw)) =
            (uint32_t)v0[j] | ((uint32_t)v1[j] << 16);
      }
    }
    // ---- compute: D[d][e] += knT-tile . vT-tile  (K = 64 = 2 slices)
#pragma unroll
    for (int ksl = 0; ksl < 2; ++ksl) {
      const int sb = (ksl * 64 + (l >> 4) * 16) ^ ((l & 8) ? 32 : 0);
      bf16x8 a[4], bb[4];
#pragma unroll
      for (int mf = 0; mf < 4; ++mf)
        a[mf] = *(const bf16x8*)(myk + (mf * 16 + (l & 15)) * 128 + sb);
#pragma unroll
      for (int nf = 0; nf < 4; ++nf)
        bb[nf] = *(const bf16x8*)(myv + (nf * 16 + (l & 15)) * 128 + sb);
#pragma unroll
      for (int mf = 0; mf < 4; ++mf)
#pragma unroll
        for (int nf = 0; nf < 4; ++nf)
          acc[mf][nf] = __builtin_amdgcn_mfma_f32_16x16x32_bf16(
              a[mf], bb[nf], acc[mf][nf], 0, 0, 0);
    }
  }

  // ---- block reduction of 4 wave partials (rows padded to 68 f32)
  __syncthreads();
  float* lf = (float*)(lds + w * 17408);
#pragma unroll
  for (int mf = 0; mf < 4; ++mf)
#pragma unroll
    for (int nf = 0; nf < 4; ++nf)
#pragma unroll
      for (int r = 0; r < 4; ++r)
        lf[(mf * 16 + (l >> 4) * 4 + r) * 68 + nf * 16 + (l & 15)] =
            acc[mf][nf][r];
  __syncthreads();
  float* op = kvp + ((size_t)(sc * 8 + b) * 16 + h) * 4096;
  const float* l0 = (const float*)lds;
  const int dd = tid >> 2, eb = (tid & 3) * 16;
#pragma unroll
  for (int c = 0; c < 4; ++c) {
    f32x4 s = *(const f32x4*)(l0 + dd * 68 + eb + c * 4);
#pragma unroll
    for (int w2 = 1; w2 < 4; ++w2)
      s += *(const f32x4*)(l0 + w2 * 4352 + dd * 68 + eb + c * 4);
    *(f32x4*)(op + tid * 16 + c * 4) = s;
  }
}

// ---------------------------------------------------------------------------
// M2 (= (1/8) kv . Wd per (b,h)) via MFMA with fused kv partial-sum; OUTPUT
// written directly in fragment-packed per-batch Bp2 layout for k_g<1>.
__global__ __launch_bounds__(256) void k_m2(const float* __restrict__ kvp,
                                            const u16* __restrict__ Wdt,
                                            u16* __restrict__ Bp2) {
  __shared__ __align__(16) u16 lds[12288];  // kv: [64][64] @0; WdT: [128][64] @4096
  const int tid = threadIdx.x;
  const int w = tid >> 6, l = tid & 63;
  const int n0 = (int)blockIdx.x * 128, h = (int)blockIdx.y,
            b = (int)blockIdx.z;

  // stage WdT tile (16KB = 1024 x 16B): row n0+(c>>3), e-slot c&7 (+h*64)
#pragma unroll
  for (int g = 0; g < 4; ++g) {
    const int c = g * 256 + tid;
    gload16(Wdt + (size_t)(n0 + (c >> 3)) * 1024 + h * 64 + (c & 7) * 8,
            lds + 4096 + (g * 256 + w * 64) * 8);
  }
  // stage kv tile with fused 4-partial sum (reg-staged, linear ds_write)
  const size_t kvbase = ((size_t)(b * 16 + h)) * 4096;
#pragma unroll
  for (int g = 0; g < 2; ++g) {
    const int c = g * 256 + tid;  // chunk: row c>>3, e-slot c&7
    const float* p = kvp + kvbase + (size_t)(c >> 3) * 64 + (c & 7) * 8;
    f32x4 s0 = *(const f32x4*)p;
    f32x4 s1 = *(const f32x4*)(p + 4);
#pragma unroll
    for (int sc = 1; sc < 4; ++sc) {
      s0 += *(const f32x4*)(p + (size_t)sc * 524288);
      s1 += *(const f32x4*)(p + (size_t)sc * 524288 + 4);
    }
    u16x8 o;
#pragma unroll
    for (int j = 0; j < 4; ++j) { o[j] = f2bf(s0[j]); o[4 + j] = f2bf(s1[j]); }
    *(u16x8*)(lds + c * 8) = o;
  }
  __syncthreads();

  f32x4 acc[4][2];
#pragma unroll
  for (int i = 0; i < 4; ++i)
#pragma unroll
    for (int j = 0; j < 2; ++j) acc[i][j] = (f32x4){0.f, 0.f, 0.f, 0.f};

#pragma unroll
  for (int kh = 0; kh < 2; ++kh) {
    bf16x8 a[4], bb[2];
#pragma unroll
    for (int mf = 0; mf < 4; ++mf)
      a[mf] = *(const bf16x8*)(lds + (mf * 16 + (l & 15)) * 64 + kh * 32 +
                               (l >> 4) * 8);
#pragma unroll
    for (int nf = 0; nf < 2; ++nf)
      bb[nf] = *(const bf16x8*)(lds + 4096 +
                                (w * 32 + nf * 16 + (l & 15)) * 64 + kh * 32 +
                                (l >> 4) * 8);
#pragma unroll
    for (int mf = 0; mf < 4; ++mf)
#pragma unroll
      for (int nf = 0; nf < 2; ++nf)
        acc[mf][nf] = __builtin_amdgcn_mfma_f32_16x16x32_bf16(
            a[mf], bb[nf], acc[mf][nf], 0, 0, 0);
  }

  // Store into fragment-packed Bp2: B^T[n][k], n = n0 + w*32 + nf*16 + (l&15),
  // k = h*64 + mf*16 + (l>>4)*4 + r. Chunk (n16, ks), lane-slot lf, u16x4.
  u16* outb = Bp2 + ((size_t)b << 20);
#pragma unroll
  for (int mf = 0; mf < 4; ++mf)
#pragma unroll
    for (int nf = 0; nf < 2; ++nf) {
      const int n16 = (n0 >> 4) + w * 2 + nf;
      const int ks = h * 2 + (mf >> 1);
      const int oct = ((mf & 1) << 1) | ((l >> 4) >> 1);
      const int within = ((l >> 4) & 1) * 4;
      const int lf = (l & 15) | (oct << 4);
      u16x4 o;
#pragma unroll
      for (int r = 0; r < 4; ++r) o[r] = f2bf(acc[mf][nf][r] * 0.125f);
      *(u16x4*)(outb + ((size_t)(n16 * 32 + ks)) * 512 + lf * 8 + within) = o;
    }
}

// ---------------------------------------------------------------------------
// LayerNorm(hid + bd + xb) * gamma + beta  -> fp32 out
__global__ __launch_bounds__(256) void k_ln(const u16* __restrict__ hid,
                                            const u16* __restrict__ xb,
                                            const float* __restrict__ bd,
                                            const float* __restrict__ g,
                                            const float* __restrict__ be,
                                            float* __restrict__ out) {
  const int tid = threadIdx.x, w = tid >> 6, l = tid & 63;
  const size_t base = (size_t)blockIdx.x * 1024 + tid * 4;
  u16x4 h4 = *(const u16x4*)(hid + base);
  u16x4 x4 = *(const u16x4*)(xb + base);
  f32x4 bd4 = *(const f32x4*)(bd + tid * 4);
  float v[4];
#pragma unroll
  for (int j = 0; j < 4; ++j) v[j] = bf2f(h4[j]) + bf2f(x4[j]) + bd4[j];
  float s = v[0] + v[1] + v[2] + v[3];
  float ss = v[0] * v[0] + v[1] * v[1] + v[2] * v[2] + v[3] * v[3];
#pragma unroll
  for (int o = 32; o > 0; o >>= 1) {
    s += __shfl_xor(s, o);
    ss += __shfl_xor(ss, o);
  }
  __shared__ float red[8];
  if (l == 0) { red[w] = s; red[w + 4] = ss; }
  __syncthreads();
  s = red[0] + red[1] + red[2] + red[3];
  ss = red[4] + red[5] + red[6] + red[7];
  const float mu = s * (1.0f / 1024.0f);
  const float var = ss * (1.0f / 1024.0f) - mu * mu;
  const float rstd = rsqrtf(var + 1e-12f);
  f32x4 g4 = *(const f32x4*)(g + tid * 4);
  f32x4 b4 = *(const f32x4*)(be + tid * 4);
  f32x4 o;
#pragma unroll
  for (int j = 0; j < 4; ++j) o[j] = (v[j] - mu) * rstd * g4[j] + b4[j];
  *(f32x4*)(out + base) = o;
}

// ---------------------------------------------------------------------------
extern "C" void kernel_launch(void* const* d_in, const int* in_sizes, int n_in,
                              void* d_out, int out_size, void* d_ws,
                              size_t ws_size, hipStream_t stream) {
  const float* X = (const float*)d_in[0];
  const float* Wq = (const float*)d_in[1];
  const float* bq = (const float*)d_in[2];
  const float* Wk = (const float*)d_in[3];
  const float* bk = (const float*)d_in[4];
  const float* Wv = (const float*)d_in[5];
  const float* bv = (const float*)d_in[6];
  const float* Wd = (const float*)d_in[7];
  const float* bd = (const float*)d_in[8];
  const float* gamma = (const float*)d_in[9];
  const float* beta = (const float*)d_in[10];
  float* out = (float*)d_out;

  char* ws = (char*)d_ws;
  u16* Xb = (u16*)(ws);                       // 64 MiB
  u16* Bp = (u16*)(ws + 67108864);            // 6 MiB  fragment-packed QKV W
  u16* eq = (u16*)(ws + 73400320);            // 64 MiB (-> qn in place)
  u16* ek = (u16*)(ws + 140509184);           // 64 MiB (raw eluK; later hid)
  u16* vb = (u16*)(ws + 207618048);           // 64 MiB
  u16* Wdt = (u16*)(ws + 274726912);          // 2 MiB  [1024][1024] bf16
  float* kvp = (float*)(ws + 276824064);      // 8 MiB (4 partials)
  u16* Bp2 = (u16*)(ws + 285212672);          // 16 MiB fragment-packed M2
  // total ws use: 301,989,888 bytes

  k_cvt_x<<<16384, 256, 0, stream>>>(X, Xb);
  k_wt<<<dim3(4, 128, 4), 256, 0, stream>>>(Wq, Wk, Wv, Wd, Bp, Wdt);
  k_g<0><<<3072, 512, 0, stream>>>(Xb, Bp, eq, ek, vb, bq, bk, bv);
  k_qn<<<8192, 256, 0, stream>>>(eq);
  k_kv<<<512, 256, 0, stream>>>(ek, vb, kvp);
  k_m2<<<dim3(8, 16, 8), 256, 0, stream>>>(kvp, Wdt, Bp2);
  k_g<1><<<1024, 512, 0, stream>>>(eq, Bp2, ek, nullptr, nullptr, nullptr,
                                   nullptr, nullptr);
  k_ln<<<32768, 256, 0, stream>>>(ek, Xb, bd, gamma, beta, out);
}

// Round 15
// 492.210 us; speedup vs baseline: 1.0341x; 1.0341x over previous
//
#include <hip/hip_runtime.h>
#include <cstdint>
#include <cstddef>

// Problem constants
#define B_ 8
#define S_ 4096
#define H_ 1024
#define NH_ 16
#define DH_ 64
#define MTOK 32768  // B_*S_

typedef unsigned short u16;
typedef __bf16 bf16x8 __attribute__((ext_vector_type(8)));
typedef u16 u16x8 __attribute__((ext_vector_type(8)));
typedef u16 u16x4 __attribute__((ext_vector_type(4)));
typedef float f32x4 __attribute__((ext_vector_type(4)));

#define DEVFN static __device__ __forceinline__

DEVFN float bf2f(u16 u) {
  union { uint32_t u; float f; } c; c.u = ((uint32_t)u) << 16; return c.f;
}
DEVFN u16 f2bf(float f) {
  union { float f; uint32_t u; } c; c.f = f;
  uint32_t r = c.u + 0x7fffu + ((c.u >> 16) & 1u);  // RNE
  return (u16)(r >> 16);
}
DEVFN void gload16(const void* g, void* lds_p) {
  __builtin_amdgcn_global_load_lds(
      (const __attribute__((address_space(1))) void*)g,
      (__attribute__((address_space(3))) void*)lds_p, 16, 0, 0);
}

// ---------------------------------------------------------------------------
// Convert fp32 X -> bf16 Xb
__global__ __launch_bounds__(256) void k_cvt_x(const float* __restrict__ x,
                                               u16* __restrict__ xb) {
  const size_t i = ((size_t)blockIdx.x * 256 + threadIdx.x) * 8;
  f32x4 a = *(const f32x4*)(x + i);
  f32x4 b = *(const f32x4*)(x + i + 4);
  u16x8 o;
#pragma unroll
  for (int j = 0; j < 4; ++j) { o[j] = f2bf(a[j]); o[4 + j] = f2bf(b[j]); }
  *(u16x8*)(xb + i) = o;
}

// ---------------------------------------------------------------------------
// Weight transposes (bf16 B^T layouts):
// g<3:  Wt[g*1024+n][k] = W_g[k][n]
// g==3: Wdt[n][e]       = Wd[e][n]
__global__ __launch_bounds__(256) void k_wt(const float* __restrict__ Wq,
                                            const float* __restrict__ Wk,
                                            const float* __restrict__ Wv,
                                            const float* __restrict__ Wd,
                                            u16* __restrict__ Wt,
                                            u16* __restrict__ Wdt) {
  const int n = blockIdx.x * 256 + threadIdx.x;  // 0..1023
  const int kc = blockIdx.y;                     // k-chunk of 8
  const int g = blockIdx.z;                      // 0..3
  const float* W = (g == 0) ? Wq : (g == 1) ? Wk : (g == 2) ? Wv : Wd;
  u16x8 o;
#pragma unroll
  for (int j = 0; j < 8; ++j) o[j] = f2bf(W[(size_t)(kc * 8 + j) * 1024 + n]);
  u16* dst = (g < 3) ? (Wt + ((size_t)(g * 1024 + n)) * 1024 + kc * 8)
                     : (Wdt + (size_t)n * 1024 + kc * 8);
  *(u16x8*)dst = o;
}

// ---------------------------------------------------------------------------
// R13 GEMM + conflict-free LDS swizzle (single change vs R13's 491us best):
// 128x256 tile, BK=64, 512 threads = 8 waves (2Mx4N), 48KB single-buffer LDS,
// plain __syncthreads per K-tile, kh-split inner loop, direct scalar stores.
// Both-sides XOR swizzle (R14-verified): 16B slot ^= (row>>1)&3, realized as
// pre-swizzled global source (linear gload_lds dest) + swizzled read offset.
// -> 8-way bank conflict (2.94x LDS cost, m136) becomes 2-way (free).
// XCD-chunked grid: xcd=bid&7 owns 32 consecutive bx; by cycles fastest.
// EPI=0: QKV (bias + elu for Q,K), grid 3072 = 8 x (12 by x 32 bx).
// EPI=1: ctx (plain store, Bt per-batch), grid 1024 = 8 x (4 by x 32 bx).
template <int EPI>
__global__ __launch_bounds__(512, 2) void k_g(
    const u16* __restrict__ A, const u16* __restrict__ Bt,
    u16* __restrict__ o0, u16* __restrict__ o1, u16* __restrict__ o2,
    const float* __restrict__ b0, const float* __restrict__ b1,
    const float* __restrict__ b2) {
  __shared__ u16 As[2 * 128 * 32];  // 16KB  [kh][128][32]
  __shared__ u16 Bs[2 * 256 * 32];  // 32KB  [kh][256][32]
  const int tid = threadIdx.x;
  const int w = tid >> 6, l = tid & 63;
  const int wm = w >> 2, wn = w & 3;  // 2M x 4N waves

  const int bid = (int)blockIdx.x;
  const int xcd = bid & 7, c = bid >> 3;
  int bx, by;
  if (EPI == 0) { by = c % 12; bx = xcd * 32 + c / 12; }
  else          { by = c & 3;  bx = xcd * 32 + (c >> 2); }

  const long row0 = (long)bx * 128;
  const long col0 = (long)by * 256;
  const u16* Bt2 = Bt + (EPI == 1 ? ((size_t)(row0 >> 12) << 20) : (size_t)0);

  f32x4 acc[4][4];
#pragma unroll
  for (int i = 0; i < 4; ++i)
#pragma unroll
    for (int j = 0; j < 4; ++j) acc[i][j] = (f32x4){0.f, 0.f, 0.f, 0.f};

  // staging: row tid>>2, 16B slot (tid&3) PRE-SWIZZLED by (row>>1)&3 =
  // (tid>>3)&3; linear LDS dest (gload_lds). Same key for A and B (row bits
  // 1-2 come from tid>>2 bits 1-2 in both; +128-row / +16-row offsets do not
  // touch the key bits).
  const int asl = ((tid & 3) ^ ((tid >> 3) & 3)) * 8;  // u16 offset
  const u16* gA = A + (row0 + (tid >> 2)) * 1024 + asl;
  const u16* gB = Bt2 + (col0 + (tid >> 2)) * 1024 + asl;
  u16* lA = As + (w * 64) * 8;  // wave-uniform
  u16* lB = Bs + (w * 64) * 8;

  // read bases: row*32 + swizzled 16B slot; slot key = (l>>1)&3
  const int rsw = (((l >> 4) ^ ((l >> 1) & 3)) << 3);
  const int aoff = (wm * 64 + (l & 15)) * 32 + rsw;
  const int boff = (wn * 64 + (l & 15)) * 32 + rsw;

  for (int kt = 0; kt < 1024; kt += 64) {
    // A: kh=0, kh=1
    gload16(gA + kt, lA);
    gload16(gA + kt + 32, lA + 4096);
    // B: i = (kh<<1)|rowhalf; dest linear chunk i*512 + tid
#pragma unroll
    for (int i = 0; i < 4; ++i) {
      const int go = (i & 1) * 131072 + (i >> 1) * 32 + kt;
      gload16(gB + go, lB + i * 4096);
    }
    __syncthreads();  // drains vmcnt -> tiles visible
#pragma unroll
    for (int kh = 0; kh < 2; ++kh) {
      bf16x8 af[4], bfr[4];
#pragma unroll
      for (int mi = 0; mi < 4; ++mi)
        af[mi] = *(const bf16x8*)(As + kh * 4096 + aoff + mi * 512);
#pragma unroll
      for (int ni = 0; ni < 4; ++ni)
        bfr[ni] = *(const bf16x8*)(Bs + kh * 8192 + boff + ni * 512);
#pragma unroll
      for (int mi = 0; mi < 4; ++mi)
#pragma unroll
        for (int ni = 0; ni < 4; ++ni)
          acc[mi][ni] = __builtin_amdgcn_mfma_f32_16x16x32_bf16(
              af[mi], bfr[ni], acc[mi][ni], 0, 0, 0);
    }
    __syncthreads();  // all reads done before next stage overwrites
  }

  // Epilogue: D row = (l>>4)*4+reg, col = l&15 within each 16x16 frag
  const int rb = (int)row0 + wm * 64 + ((l >> 4) << 2);
  const int cb = (int)col0 + wn * 64 + (l & 15);
  if (EPI == 0) {
    const int seg = (int)(col0 >> 10);  // 0:Q 1:K 2:V (uniform per block)
    const int cl = cb & 1023;
    u16* outp = (seg == 0) ? o0 : (seg == 1) ? o1 : o2;
    const float* bias = (seg == 0) ? b0 : (seg == 1) ? b1 : b2;
#pragma unroll
    for (int mi = 0; mi < 4; ++mi)
#pragma unroll
      for (int ni = 0; ni < 4; ++ni) {
        const float bv_ = bias[cl + ni * 16];
#pragma unroll
        for (int r = 0; r < 4; ++r) {
          float v = acc[mi][ni][r] + bv_;
          if (seg < 2) v = v > 0.f ? v : expm1f(v);  // elu
          outp[(size_t)(rb + mi * 16 + r) * 1024 + cl + ni * 16] = f2bf(v);
        }
      }
  } else {
#pragma unroll
    for (int mi = 0; mi < 4; ++mi)
#pragma unroll
      for (int ni = 0; ni < 4; ++ni)
#pragma unroll
        for (int r = 0; r < 4; ++r)
          o0[(size_t)(rb + mi * 16 + r) * 1024 + cb + ni * 16] =
              f2bf(acc[mi][ni][r]);
  }
}

// ---------------------------------------------------------------------------
// Per-(token,head) L2 norm for Q only, in place (K norm fused into k_kv).
__global__ __launch_bounds__(256) void k_qn(u16* __restrict__ eq) {
  const int tid = threadIdx.x, w = tid >> 6, l = tid & 63;
  const long t = (long)blockIdx.x * 4 + w;
  const size_t base = (size_t)t * 1024 + (l >> 2) * 64 + (l & 3) * 16;
  u16x8 a = *(const u16x8*)(eq + base);
  u16x8 b = *(const u16x8*)(eq + base + 8);
  float f[16];
#pragma unroll
  for (int j = 0; j < 8; ++j) { f[j] = bf2f(a[j]); f[8 + j] = bf2f(b[j]); }
  float ss = 0.f;
#pragma unroll
  for (int j = 0; j < 16; ++j) ss += f[j] * f[j];
  ss += __shfl_xor(ss, 1);
  ss += __shfl_xor(ss, 2);
  const float rq = rsqrtf(ss);
  u16x8 oa, ob;
#pragma unroll
  for (int j = 0; j < 8; ++j) { oa[j] = f2bf(f[j] * rq); ob[j] = f2bf(f[8 + j] * rq); }
  *(u16x8*)(eq + base) = oa;
  *(u16x8*)(eq + base + 8) = ob;
}

// ---------------------------------------------------------------------------
// kv partials via MFMA with FUSED K-normalization:
// kvp[sc][b][h][d][e] = sum_{s in quarter} (ek[s,d]/||ek[s,:]||) * v[s,e]
__global__ __launch_bounds__(256) void k_kv(const u16* __restrict__ ek,
                                            const u16* __restrict__ vv,
                                            float* __restrict__ kvp) {
  __shared__ __align__(16) char lds[69632];  // 4 regions x 17408 B
  const int tid = threadIdx.x, w = tid >> 6, l = tid & 63;
  const int bid = blockIdx.x;  // sc + 4*(h + 16*b)
  const int sc = bid & 3, h = (bid >> 2) & 15, b = bid >> 6;
  const int tp = l >> 3, dgrp = l & 7;
  char* myk = lds + w * 17408;       // knT tile [64 d][64 s] u16 (128B rows)
  char* myv = myk + 8192;            // vT tile
  const long Tw = (long)b * 4096 + sc * 1024 + w * 256;
  const int d0 = dgrp * 8;

  f32x4 acc[4][4];
#pragma unroll
  for (int i = 0; i < 4; ++i)
#pragma unroll
    for (int j = 0; j < 4; ++j) acc[i][j] = (f32x4){0.f, 0.f, 0.f, 0.f};

  for (int st = 0; st < 4; ++st) {
    // ---- transpose-stage 64 tokens x 64 d for kn (normalized) and v
#pragma unroll
    for (int ro = 0; ro < 4; ++ro) {
      const int tl = ro * 16 + tp * 2;  // even local token
      const long T = Tw + st * 64 + tl;
      const u16* kp = ek + (size_t)T * 1024 + h * 64 + d0;
      const u16* vp = vv + (size_t)T * 1024 + h * 64 + d0;
      u16x8 k0 = *(const u16x8*)kp, k1 = *(const u16x8*)(kp + 1024);
      u16x8 v0 = *(const u16x8*)vp, v1 = *(const u16x8*)(vp + 1024);
      float f0[8], f1[8], s0 = 0.f, s1 = 0.f;
#pragma unroll
      for (int j = 0; j < 8; ++j) {
        f0[j] = bf2f(k0[j]); s0 += f0[j] * f0[j];
        f1[j] = bf2f(k1[j]); s1 += f1[j] * f1[j];
      }
      s0 += __shfl_xor(s0, 1); s0 += __shfl_xor(s0, 2); s0 += __shfl_xor(s0, 4);
      s1 += __shfl_xor(s1, 1); s1 += __shfl_xor(s1, 2); s1 += __shfl_xor(s1, 4);
      const float r0 = rsqrtf(s0), r1 = rsqrtf(s1);
#pragma unroll
      for (int j = 0; j < 8; ++j) {
        const int d = d0 + j;
        const int sw = (d & 8) ? 32 : 0;
        *(uint32_t*)(myk + d * 128 + ((tl * 2) ^ sw)) =
            (uint32_t)f2bf(f0[j] * r0) | ((uint32_t)f2bf(f1[j] * r1) << 16);
        *(uint32_t*)(myv + d * 128 + ((tl * 2) ^ sw)) =
            (uint32_t)v0[j] | ((uint32_t)v1[j] << 16);
      }
    }
    // ---- compute: D[d][e] += knT-tile . vT-tile  (K = 64 = 2 slices)
#pragma unroll
    for (int ksl = 0; ksl < 2; ++ksl) {
      const int sb = (ksl * 64 + (l >> 4) * 16) ^ ((l & 8) ? 32 : 0);
      bf16x8 a[4], bb[4];
#pragma unroll
      for (int mf = 0; mf < 4; ++mf)
        a[mf] = *(const bf16x8*)(myk + (mf * 16 + (l & 15)) * 128 + sb);
#pragma unroll
      for (int nf = 0; nf < 4; ++nf)
        bb[nf] = *(const bf16x8*)(myv + (nf * 16 + (l & 15)) * 128 + sb);
#pragma unroll
      for (int mf = 0; mf < 4; ++mf)
#pragma unroll
        for (int nf = 0; nf < 4; ++nf)
          acc[mf][nf] = __builtin_amdgcn_mfma_f32_16x16x32_bf16(
              a[mf], bb[nf], acc[mf][nf], 0, 0, 0);
    }
  }

  // ---- block reduction of 4 wave partials (rows padded to 68 f32)
  __syncthreads();
  float* lf = (float*)(lds + w * 17408);
#pragma unroll
  for (int mf = 0; mf < 4; ++mf)
#pragma unroll
    for (int nf = 0; nf < 4; ++nf)
#pragma unroll
      for (int r = 0; r < 4; ++r)
        lf[(mf * 16 + (l >> 4) * 4 + r) * 68 + nf * 16 + (l & 15)] =
            acc[mf][nf][r];
  __syncthreads();
  float* op = kvp + ((size_t)(sc * 8 + b) * 16 + h) * 4096;
  const float* l0 = (const float*)lds;
  const int dd = tid >> 2, eb = (tid & 3) * 16;
#pragma unroll
  for (int c = 0; c < 4; ++c) {
    f32x4 s = *(const f32x4*)(l0 + dd * 68 + eb + c * 4);
#pragma unroll
    for (int w2 = 1; w2 < 4; ++w2)
      s += *(const f32x4*)(l0 + w2 * 4352 + dd * 68 + eb + c * 4);
    *(f32x4*)(op + tid * 16 + c * 4) = s;
  }
}

// ---------------------------------------------------------------------------
// M2t[b][n][h*64+d] = (1/8) * sum_e kv[b,h][d][e] * Wdt[n][h*64+e] via MFMA,
// with FUSED kv partial-sum (reads the 4 kvp partials, sums in reg, stages
// bf16 tile to LDS).
__global__ __launch_bounds__(256) void k_m2(const float* __restrict__ kvp,
                                            const u16* __restrict__ Wdt,
                                            u16* __restrict__ M2t) {
  __shared__ __align__(16) u16 lds[12288];  // kv: [64][64] @0; WdT: [128][64] @4096
  const int tid = threadIdx.x;
  const int w = tid >> 6, l = tid & 63;
  const int n0 = (int)blockIdx.x * 128, h = (int)blockIdx.y,
            b = (int)blockIdx.z;

  // stage WdT tile (16KB = 1024 x 16B): row n0+(c>>3), e-slot c&7 (+h*64)
#pragma unroll
  for (int g = 0; g < 4; ++g) {
    const int c = g * 256 + tid;
    gload16(Wdt + (size_t)(n0 + (c >> 3)) * 1024 + h * 64 + (c & 7) * 8,
            lds + 4096 + (g * 256 + w * 64) * 8);
  }
  // stage kv tile with fused 4-partial sum (reg-staged, linear ds_write)
  const size_t kvbase = ((size_t)(b * 16 + h)) * 4096;
#pragma unroll
  for (int g = 0; g < 2; ++g) {
    const int c = g * 256 + tid;  // chunk: row c>>3, e-slot c&7
    const float* p = kvp + kvbase + (size_t)(c >> 3) * 64 + (c & 7) * 8;
    f32x4 s0 = *(const f32x4*)p;
    f32x4 s1 = *(const f32x4*)(p + 4);
#pragma unroll
    for (int sc = 1; sc < 4; ++sc) {
      s0 += *(const f32x4*)(p + (size_t)sc * 524288);
      s1 += *(const f32x4*)(p + (size_t)sc * 524288 + 4);
    }
    u16x8 o;
#pragma unroll
    for (int j = 0; j < 4; ++j) { o[j] = f2bf(s0[j]); o[4 + j] = f2bf(s1[j]); }
    *(u16x8*)(lds + c * 8) = o;
  }
  __syncthreads();

  f32x4 acc[4][2];
#pragma unroll
  for (int i = 0; i < 4; ++i)
#pragma unroll
    for (int j = 0; j < 2; ++j) acc[i][j] = (f32x4){0.f, 0.f, 0.f, 0.f};

#pragma unroll
  for (int kh = 0; kh < 2; ++kh) {
    bf16x8 a[4], bb[2];
#pragma unroll
    for (int mf = 0; mf < 4; ++mf)
      a[mf] = *(const bf16x8*)(lds + (mf * 16 + (l & 15)) * 64 + kh * 32 +
                               (l >> 4) * 8);
#pragma unroll
    for (int nf = 0; nf < 2; ++nf)
      bb[nf] = *(const bf16x8*)(lds + 4096 +
                                (w * 32 + nf * 16 + (l & 15)) * 64 + kh * 32 +
                                (l >> 4) * 8);
#pragma unroll
    for (int mf = 0; mf < 4; ++mf)
#pragma unroll
      for (int nf = 0; nf < 2; ++nf)
        acc[mf][nf] = __builtin_amdgcn_mfma_f32_16x16x32_bf16(
            a[mf], bb[nf], acc[mf][nf], 0, 0, 0);
  }

  // store: D[d][n]; col n = w*32+nf*16+(l&15); rows d = mf*16+(l>>4)*4+r
  u16* outb = M2t + ((size_t)b << 20) + h * 64;
#pragma unroll
  for (int mf = 0; mf < 4; ++mf)
#pragma unroll
    for (int nf = 0; nf < 2; ++nf) {
      const int col = w * 32 + nf * 16 + (l & 15);
      u16x4 o;
#pragma unroll
      for (int r = 0; r < 4; ++r) o[r] = f2bf(acc[mf][nf][r] * 0.125f);
      *(u16x4*)(outb + (size_t)(n0 + col) * 1024 + mf * 16 + (l >> 4) * 4) = o;
    }
}

// ---------------------------------------------------------------------------
// LayerNorm(hid + bd + xb) * gamma + beta  -> fp32 out
__global__ __launch_bounds__(256) void k_ln(const u16* __restrict__ hid,
                                            const u16* __restrict__ xb,
                                            const float* __restrict__ bd,
                                            const float* __restrict__ g,
                                            const float* __restrict__ be,
                                            float* __restrict__ out) {
  const int tid = threadIdx.x, w = tid >> 6, l = tid & 63;
  const size_t base = (size_t)blockIdx.x * 1024 + tid * 4;
  u16x4 h4 = *(const u16x4*)(hid + base);
  u16x4 x4 = *(const u16x4*)(xb + base);
  f32x4 bd4 = *(const f32x4*)(bd + tid * 4);
  float v[4];
#pragma unroll
  for (int j = 0; j < 4; ++j) v[j] = bf2f(h4[j]) + bf2f(x4[j]) + bd4[j];
  float s = v[0] + v[1] + v[2] + v[3];
  float ss = v[0] * v[0] + v[1] * v[1] + v[2] * v[2] + v[3] * v[3];
#pragma unroll
  for (int o = 32; o > 0; o >>= 1) {
    s += __shfl_xor(s, o);
    ss += __shfl_xor(ss, o);
  }
  __shared__ float red[8];
  if (l == 0) { red[w] = s; red[w + 4] = ss; }
  __syncthreads();
  s = red[0] + red[1] + red[2] + red[3];
  ss = red[4] + red[5] + red[6] + red[7];
  const float mu = s * (1.0f / 1024.0f);
  const float var = ss * (1.0f / 1024.0f) - mu * mu;
  const float rstd = rsqrtf(var + 1e-12f);
  f32x4 g4 = *(const f32x4*)(g + tid * 4);
  f32x4 b4 = *(const f32x4*)(be + tid * 4);
  f32x4 o;
#pragma unroll
  for (int j = 0; j < 4; ++j) o[j] = (v[j] - mu) * rstd * g4[j] + b4[j];
  *(f32x4*)(out + base) = o;
}

// ---------------------------------------------------------------------------
extern "C" void kernel_launch(void* const* d_in, const int* in_sizes, int n_in,
                              void* d_out, int out_size, void* d_ws,
                              size_t ws_size, hipStream_t stream) {
  const float* X = (const float*)d_in[0];
  const float* Wq = (const float*)d_in[1];
  const float* bq = (const float*)d_in[2];
  const float* Wk = (const float*)d_in[3];
  const float* bk = (const float*)d_in[4];
  const float* Wv = (const float*)d_in[5];
  const float* bv = (const float*)d_in[6];
  const float* Wd = (const float*)d_in[7];
  const float* bd = (const float*)d_in[8];
  const float* gamma = (const float*)d_in[9];
  const float* beta = (const float*)d_in[10];
  float* out = (float*)d_out;

  char* ws = (char*)d_ws;
  u16* Xb = (u16*)(ws);                       // 64 MiB
  u16* Wt = (u16*)(ws + 67108864);            // 6 MiB  [3072][1024] bf16
  u16* eq = (u16*)(ws + 73400320);            // 64 MiB (-> qn in place)
  u16* ek = (u16*)(ws + 140509184);           // 64 MiB (raw eluK; later hid)
  u16* vb = (u16*)(ws + 207618048);           // 64 MiB
  u16* Wdt = (u16*)(ws + 274726912);          // 2 MiB  [1024][1024] bf16
  float* kvp = (float*)(ws + 276824064);      // 8 MiB (4 partials)
  u16* M2t = (u16*)(ws + 285212672);          // 16 MiB  [8][1024][1024] bf16
  // total ws use: 301,989,888 bytes

  k_cvt_x<<<16384, 256, 0, stream>>>(X, Xb);
  k_wt<<<dim3(4, 128, 4), 256, 0, stream>>>(Wq, Wk, Wv, Wd, Wt, Wdt);
  k_g<0><<<3072, 512, 0, stream>>>(Xb, Wt, eq, ek, vb, bq, bk, bv);
  k_qn<<<8192, 256, 0, stream>>>(eq);
  k_kv<<<512, 256, 0, stream>>>(ek, vb, kvp);
  k_m2<<<dim3(8, 16, 8), 256, 0, stream>>>(kvp, Wdt, M2t);
  k_g<1><<<1024, 512, 0, stream>>>(eq, M2t, ek, nullptr, nullptr, nullptr,
                                   nullptr, nullptr);
  k_ln<<<32768, 256, 0, stream>>>(ek, Xb, bd, gamma, beta, out);
}